// Round 1
// baseline (113.478 us; speedup 1.0000x reference)
//
#include <hip/hip_runtime.h>
#include <math.h>

// QuantumConv: per-pixel 6-qubit circuit collapses to 6 real 8x8 quadratic
// forms q_w = r^T G_w r (subspace trick: wires 3-5 start at |0>, circuit
// unitary depends only on `weights`). Kernel 1 builds G (1.5 KB) from the
// weights; kernel 2 fuses pool+quantum+fc+LN+ReLU+bilinear-2x-upsample.

#define HP 112   // low-res H (=224/2)
#define WP 112

// ---------------- Kernel 1: build G[6][8][8] from weights ----------------
__global__ void build_G(const float* __restrict__ wts, float* __restrict__ G) {
    __shared__ float2 cs[64][8];   // V[s][a]: columns = circuit applied to subspace basis
    __shared__ float  U[24][8];    // per-gate 2x2 complex (re,im): U00 U01 U10 U11
    int t = threadIdx.x;           // 64 threads

    if (t < 24) {   // one gate per thread: Rot(phi, theta, omega)
        float phi = wts[t*3+0], th = wts[t*3+1], om = wts[t*3+2];
        float cth, sth, cap, sap, cam, sam;
        sincosf(0.5f*th, &sth, &cth);
        sincosf(0.5f*(phi+om), &sap, &cap);   // ep = cap - i*sap
        sincosf(0.5f*(phi-om), &sam, &cam);   // em = cam - i*sam
        U[t][0] =  cap*cth; U[t][1] = -sap*cth;   // U00 = ep*c
        U[t][2] = -cam*sth; U[t][3] = -sam*sth;   // U01 = -conj(em)*s
        U[t][4] =  cam*sth; U[t][5] = -sam*sth;   // U10 = em*s
        U[t][6] =  cap*cth; U[t][7] =  sap*cth;   // U11 = conj(ep)*c
    }
    #pragma unroll
    for (int a = 0; a < 8; ++a)
        cs[t][a] = make_float2((t == a*8) ? 1.0f : 0.0f, 0.0f);  // subspace: bits 3..5 = 0
    __syncthreads();

    for (int l = 0; l < 4; ++l) {
        // single-qubit rotations (wire 0 = MSB, mask 1<<(5-w))
        for (int w = 0; w < 6; ++w) {
            int g = l*6 + w;
            float u00r=U[g][0],u00i=U[g][1],u01r=U[g][2],u01i=U[g][3],
                  u10r=U[g][4],u10i=U[g][5],u11r=U[g][6],u11i=U[g][7];
            int m = 1 << (5 - w);
            for (int it = t; it < 256; it += 64) {       // 32 pairs x 8 cols
                int a = it & 7, p = it >> 3;
                int low = p & (m - 1);
                int s0 = ((p ^ low) << 1) | low;         // insert 0-bit at mask pos
                int s1 = s0 | m;
                float2 v0 = cs[s0][a], v1 = cs[s1][a];
                cs[s0][a] = make_float2(u00r*v0.x - u00i*v0.y + u01r*v1.x - u01i*v1.y,
                                        u00r*v0.y + u00i*v0.x + u01r*v1.y + u01i*v1.x);
                cs[s1][a] = make_float2(u10r*v0.x - u10i*v0.y + u11r*v1.x - u11i*v1.y,
                                        u10r*v0.y + u10i*v0.x + u11r*v1.y + u11i*v1.x);
            }
            __syncthreads();
        }
        // CNOT ring: control w, target (w+r)%6, applied sequentially
        int r = l % 5 + 1;
        for (int w = 0; w < 6; ++w) {
            int mc = 1 << (5 - w), mt = 1 << (5 - ((w + r) % 6));
            for (int it = t; it < 128; it += 64) {       // 16 states x 8 cols
                int a = it & 7, p = it >> 3;
                int s = 0, pp = p;
                #pragma unroll
                for (int bit = 0; bit < 6; ++bit) {
                    int mm = 1 << bit;
                    if (mm == mc || mm == mt) continue;
                    if (pp & 1) s |= mm;
                    pp >>= 1;
                }
                s |= mc;                                  // control=1, target=0
                float2 v0 = cs[s][a], v1 = cs[s | mt][a];
                cs[s][a] = v1; cs[s | mt][a] = v0;        // swap target amplitudes
            }
            __syncthreads();
        }
    }

    // G_w[a][b] = Re( i^(pop(a)-pop(b)) * sum_s z_w(s) conj(V[s,a]) V[s,b] )
    for (int o = t; o < 384; o += 64) {
        int w = o >> 6, a = (o >> 3) & 7, bb = o & 7;
        int mw = 1 << (5 - w);
        float re = 0.f, im = 0.f;
        for (int s = 0; s < 64; ++s) {
            float z = (s & mw) ? -1.f : 1.f;
            float2 va = cs[s][a], vb = cs[s][bb];
            re += z * (va.x*vb.x + va.y*vb.y);
            im += z * (va.x*vb.y - va.y*vb.x);
        }
        int d = (__popc(a) - __popc(bb)) & 3;   // conj(f_a)*f_b = i^d
        G[o] = (d == 0) ? re : (d == 1) ? -im : (d == 2) ? -re : im;
    }
}

// ---------------- Kernel 2: fused pool+quantum+fc+LN+ReLU+upsample ----------------
// Block: batch b, 16(oh) x 32(ow) output tile -> needs 10 x 18 low-res y tile.
__global__ __launch_bounds__(256) void fused(
    const float* __restrict__ x, const float* __restrict__ fcw,
    const float* __restrict__ fcb, const float* __restrict__ lng,
    const float* __restrict__ lnb, const float* __restrict__ G,
    float* __restrict__ out) {

    __shared__ __align__(16) float Gs[384];
    __shared__ float fcwS[96], fcbS[16], lngS[16], lnbS[16];
    __shared__ float yS[16][10][18];   // [c][row][col] -> conflict-free interp reads

    int tid = threadIdx.x;
    int b   = blockIdx.z;
    int ow0 = blockIdx.x * 32, oh0 = blockIdx.y * 16;
    int w0  = blockIdx.x * 16, k0  = blockIdx.y * 8;   // low-res tile origin

    for (int i = tid; i < 384; i += 256) Gs[i] = G[i];
    for (int i = tid; i < 96;  i += 256) fcwS[i] = fcw[i];
    if (tid < 16) { fcbS[tid] = fcb[tid]; lngS[tid] = lng[tid]; lnbS[tid] = lnb[tid]; }
    __syncthreads();

    if (tid < 180) {   // 10 x 18 low-res pixels (1-halo for bilinear)
        int pr = tid / 18, pc = tid % 18;
        int ih = min(max(k0 - 1 + pr, 0), HP - 1);
        int iw = min(max(w0 - 1 + pc, 0), WP - 1);

        // 2x2 mean pool, 3 channels
        float m[3];
        #pragma unroll
        for (int c = 0; c < 3; ++c) {
            const float2* px = reinterpret_cast<const float2*>(
                x + (((b*3 + c)*224 + 2*ih)*224 + 2*iw));
            float2 r0 = px[0], r1 = px[112];
            m[c] = 0.25f * (r0.x + r0.y + r1.x + r1.y);
        }

        float cc[3], ssn[3];
        #pragma unroll
        for (int c = 0; c < 3; ++c) sincosf(0.5f*m[c], &ssn[c], &cc[c]);

        float r8[8] = { cc[0]*cc[1]*cc[2], cc[0]*cc[1]*ssn[2],
                        cc[0]*ssn[1]*cc[2], cc[0]*ssn[1]*ssn[2],
                        ssn[0]*cc[1]*cc[2], ssn[0]*cc[1]*ssn[2],
                        ssn[0]*ssn[1]*cc[2], ssn[0]*ssn[1]*ssn[2] };

        // q_w = r^T G_w r  (ds_read_b128 on Gs)
        float q[6];
        const float4* G4 = reinterpret_cast<const float4*>(Gs);
        #pragma unroll
        for (int w = 0; w < 6; ++w) {
            float acc = 0.f;
            #pragma unroll
            for (int a = 0; a < 8; ++a) {
                float4 g0 = G4[w*16 + a*2], g1 = G4[w*16 + a*2 + 1];
                float d = g0.x*r8[0] + g0.y*r8[1] + g0.z*r8[2] + g0.w*r8[3]
                        + g1.x*r8[4] + g1.y*r8[5] + g1.z*r8[6] + g1.w*r8[7];
                acc += r8[a] * d;
            }
            q[w] = acc;
        }

        // fc -> LayerNorm -> ReLU
        float y[16]; float mu = 0.f;
        #pragma unroll
        for (int c = 0; c < 16; ++c) {
            float v = fcbS[c];
            #pragma unroll
            for (int w = 0; w < 6; ++w) v += fcwS[c*6 + w] * q[w];
            y[c] = v; mu += v;
        }
        mu *= 0.0625f;
        float var = 0.f;
        #pragma unroll
        for (int c = 0; c < 16; ++c) { float d = y[c] - mu; var += d*d; }
        var *= 0.0625f;
        float inv = 1.0f / sqrtf(var + 1e-5f);
        #pragma unroll
        for (int c = 0; c < 16; ++c) {
            float v = (y[c] - mu) * inv * lngS[c] + lnbS[c];
            yS[c][pr][pc] = fmaxf(v, 0.f);
        }
    }
    __syncthreads();

    // bilinear 2x upsample (jax.image.resize half-pixel: weights 0.75/0.25,
    // edge renormalization == clamped indices). 8192 outputs / 256 threads.
    for (int it = tid; it < 8192; it += 256) {
        int c = it >> 9, rem = it & 511, ohl = rem >> 5, owl = rem & 31;
        int oh = oh0 + ohl, ow = ow0 + owl;
        int kh = oh >> 1, kw = ow >> 1;
        int ha, hb, ta, tb; float wha, wwa;
        if (oh & 1) { ha = kh;     hb = kh + 1; wha = 0.75f; }
        else        { ha = kh - 1; hb = kh;     wha = 0.25f; }
        if (ow & 1) { ta = kw;     tb = kw + 1; wwa = 0.75f; }
        else        { ta = kw - 1; tb = kw;     wwa = 0.25f; }
        ha = min(max(ha, 0), HP - 1) - (k0 - 1);
        hb = min(max(hb, 0), HP - 1) - (k0 - 1);
        ta = min(max(ta, 0), WP - 1) - (w0 - 1);
        tb = min(max(tb, 0), WP - 1) - (w0 - 1);
        float whb = 1.f - wha, wwb = 1.f - wwa;
        float v = wha * (wwa * yS[c][ha][ta] + wwb * yS[c][ha][tb])
                + whb * (wwa * yS[c][hb][ta] + wwb * yS[c][hb][tb]);
        out[((b*16 + c)*224 + oh)*224 + ow] = v;
    }
}

extern "C" void kernel_launch(void* const* d_in, const int* in_sizes, int n_in,
                              void* d_out, int out_size, void* d_ws, size_t ws_size,
                              hipStream_t stream) {
    const float* x   = (const float*)d_in[0];
    const float* wts = (const float*)d_in[1];
    const float* fcw = (const float*)d_in[2];
    const float* fcb = (const float*)d_in[3];
    const float* lng = (const float*)d_in[4];
    const float* lnb = (const float*)d_in[5];
    float* G   = (float*)d_ws;        // 384 floats
    float* out = (float*)d_out;

    build_G<<<1, 64, 0, stream>>>(wts, G);
    fused<<<dim3(7, 14, 8), 256, 0, stream>>>(x, fcw, fcb, lng, lnb, G, out);
}

// Round 2
// 106.478 us; speedup vs baseline: 1.0657x; 1.0657x over previous
//
#include <hip/hip_runtime.h>
#include <math.h>

// QuantumConv: per-pixel 6-qubit circuit collapses to 6 real 8x8 quadratic
// forms q_w = r^T G_w r (subspace trick: wires 3-5 start at |0>, circuit
// unitary depends only on `weights`). Kernel 1 builds G (1.5 KB) from the
// weights; kernel 2 fuses pool+quantum+fc+LN+ReLU+bilinear-2x-upsample.
//
// R2: build_G rewritten as a register/shfl butterfly — lane t holds state
// amplitude s=t for all 8 subspace columns; gates are __shfl_xor + FMA
// (no LDS, no barriers in the 48-gate chain). Was ~48 syncthreads + LDS
// round-trip per gate on a single wave = pure latency chain.

#define HP 112   // low-res H (=224/2)
#define WP 112

// ---------------- Kernel 1: build G[6][8][8] from weights ----------------
__global__ void build_G(const float* __restrict__ wts, float* __restrict__ G) {
    __shared__ float  U[24][8];    // per-gate 2x2 complex (re,im): U00 U01 U10 U11
    __shared__ float2 cs[64][8];   // V[s][a] staged only for the final reduction
    int t = threadIdx.x;           // 64 threads = 1 wave

    if (t < 24) {   // one gate per thread: Rot(phi, theta, omega)
        float phi = wts[t*3+0], th = wts[t*3+1], om = wts[t*3+2];
        float cth, sth, cap, sap, cam, sam;
        sincosf(0.5f*th, &sth, &cth);
        sincosf(0.5f*(phi+om), &sap, &cap);   // ep = cap - i*sap
        sincosf(0.5f*(phi-om), &sam, &cam);   // em = cam - i*sam
        U[t][0] =  cap*cth; U[t][1] = -sap*cth;   // U00 = ep*c
        U[t][2] = -cam*sth; U[t][3] = -sam*sth;   // U01 = -conj(em)*s
        U[t][4] =  cam*sth; U[t][5] = -sam*sth;   // U10 = em*s
        U[t][6] =  cap*cth; U[t][7] =  sap*cth;   // U11 = conj(ep)*c
    }
    __syncthreads();

    // lane t = state index; v[a] = amplitude of column a (subspace basis a<<3)
    float2 v[8];
    #pragma unroll
    for (int a = 0; a < 8; ++a)
        v[a] = make_float2((t == (a << 3)) ? 1.0f : 0.0f, 0.0f);

    for (int l = 0; l < 4; ++l) {
        // single-qubit rotations (wire 0 = MSB, mask 1<<(5-w))
        for (int w = 0; w < 6; ++w) {
            int g = l*6 + w, m = 1 << (5 - w);
            bool hi = (t & m) != 0;
            // self/partner coefficients per lane side
            float csr = hi ? U[g][6] : U[g][0], csi = hi ? U[g][7] : U[g][1];
            float cpr = hi ? U[g][4] : U[g][2], cpi = hi ? U[g][5] : U[g][3];
            #pragma unroll
            for (int a = 0; a < 8; ++a) {
                float px = __shfl_xor(v[a].x, m), py = __shfl_xor(v[a].y, m);
                v[a] = make_float2(csr*v[a].x - csi*v[a].y + cpr*px - cpi*py,
                                   csr*v[a].y + csi*v[a].x + cpr*py + cpi*px);
            }
        }
        // CNOT ring: control w, target (w+r)%6 — swap target bit where control=1
        int r = l % 5 + 1;
        for (int w = 0; w < 6; ++w) {
            int mc = 1 << (5 - w), mt = 1 << (5 - ((w + r) % 6));
            bool ctrl = (t & mc) != 0;
            #pragma unroll
            for (int a = 0; a < 8; ++a) {
                float px = __shfl_xor(v[a].x, mt), py = __shfl_xor(v[a].y, mt);
                if (ctrl) v[a] = make_float2(px, py);
            }
        }
    }

    #pragma unroll
    for (int a = 0; a < 8; ++a) cs[t][a] = v[a];
    __syncthreads();

    // G_w[a][b] = Re( i^(pop(a)-pop(b)) * sum_s z_w(s) conj(V[s,a]) V[s,b] )
    for (int o = t; o < 384; o += 64) {
        int w = o >> 6, a = (o >> 3) & 7, bb = o & 7;
        int mw = 1 << (5 - w);
        float re = 0.f, im = 0.f;
        for (int s = 0; s < 64; ++s) {
            float z = (s & mw) ? -1.f : 1.f;
            float2 va = cs[s][a], vb = cs[s][bb];
            re += z * (va.x*vb.x + va.y*vb.y);
            im += z * (va.x*vb.y - va.y*vb.x);
        }
        int d = (__popc(a) - __popc(bb)) & 3;   // conj(f_a)*f_b = i^d
        G[o] = (d == 0) ? re : (d == 1) ? -im : (d == 2) ? -re : im;
    }
}

// ---------------- Kernel 2: fused pool+quantum+fc+LN+ReLU+upsample ----------------
// Block: batch b, 16(oh) x 32(ow) output tile -> needs 10 x 18 low-res y tile.
__global__ __launch_bounds__(256) void fused(
    const float* __restrict__ x, const float* __restrict__ fcw,
    const float* __restrict__ fcb, const float* __restrict__ lng,
    const float* __restrict__ lnb, const float* __restrict__ G,
    float* __restrict__ out) {

    __shared__ __align__(16) float Gs[384];
    __shared__ float fcwS[96], fcbS[16], lngS[16], lnbS[16];
    __shared__ float yS[16][10][18];   // [c][row][col] -> conflict-free interp reads

    int tid = threadIdx.x;
    int b   = blockIdx.z;
    int ow0 = blockIdx.x * 32, oh0 = blockIdx.y * 16;
    int w0  = blockIdx.x * 16, k0  = blockIdx.y * 8;   // low-res tile origin

    for (int i = tid; i < 384; i += 256) Gs[i] = G[i];
    for (int i = tid; i < 96;  i += 256) fcwS[i] = fcw[i];
    if (tid < 16) { fcbS[tid] = fcb[tid]; lngS[tid] = lng[tid]; lnbS[tid] = lnb[tid]; }
    __syncthreads();

    if (tid < 180) {   // 10 x 18 low-res pixels (1-halo for bilinear)
        int pr = tid / 18, pc = tid % 18;
        int ih = min(max(k0 - 1 + pr, 0), HP - 1);
        int iw = min(max(w0 - 1 + pc, 0), WP - 1);

        // 2x2 mean pool, 3 channels
        float m[3];
        #pragma unroll
        for (int c = 0; c < 3; ++c) {
            const float2* px = reinterpret_cast<const float2*>(
                x + (((b*3 + c)*224 + 2*ih)*224 + 2*iw));
            float2 r0 = px[0], r1 = px[112];
            m[c] = 0.25f * (r0.x + r0.y + r1.x + r1.y);
        }

        float cc[3], ssn[3];
        #pragma unroll
        for (int c = 0; c < 3; ++c) sincosf(0.5f*m[c], &ssn[c], &cc[c]);

        float r8[8] = { cc[0]*cc[1]*cc[2], cc[0]*cc[1]*ssn[2],
                        cc[0]*ssn[1]*cc[2], cc[0]*ssn[1]*ssn[2],
                        ssn[0]*cc[1]*cc[2], ssn[0]*cc[1]*ssn[2],
                        ssn[0]*ssn[1]*cc[2], ssn[0]*ssn[1]*ssn[2] };

        // q_w = r^T G_w r  (ds_read_b128 on Gs)
        float q[6];
        const float4* G4 = reinterpret_cast<const float4*>(Gs);
        #pragma unroll
        for (int w = 0; w < 6; ++w) {
            float acc = 0.f;
            #pragma unroll
            for (int a = 0; a < 8; ++a) {
                float4 g0 = G4[w*16 + a*2], g1 = G4[w*16 + a*2 + 1];
                float d = g0.x*r8[0] + g0.y*r8[1] + g0.z*r8[2] + g0.w*r8[3]
                        + g1.x*r8[4] + g1.y*r8[5] + g1.z*r8[6] + g1.w*r8[7];
                acc += r8[a] * d;
            }
            q[w] = acc;
        }

        // fc -> LayerNorm -> ReLU
        float y[16]; float mu = 0.f;
        #pragma unroll
        for (int c = 0; c < 16; ++c) {
            float v = fcbS[c];
            #pragma unroll
            for (int w = 0; w < 6; ++w) v += fcwS[c*6 + w] * q[w];
            y[c] = v; mu += v;
        }
        mu *= 0.0625f;
        float var = 0.f;
        #pragma unroll
        for (int c = 0; c < 16; ++c) { float d = y[c] - mu; var += d*d; }
        var *= 0.0625f;
        float inv = 1.0f / sqrtf(var + 1e-5f);
        #pragma unroll
        for (int c = 0; c < 16; ++c) {
            float v = (y[c] - mu) * inv * lngS[c] + lnbS[c];
            yS[c][pr][pc] = fmaxf(v, 0.f);
        }
    }
    __syncthreads();

    // bilinear 2x upsample (jax.image.resize half-pixel: weights 0.75/0.25,
    // edge renormalization == clamped indices). 8192 outputs / 256 threads.
    for (int it = tid; it < 8192; it += 256) {
        int c = it >> 9, rem = it & 511, ohl = rem >> 5, owl = rem & 31;
        int oh = oh0 + ohl, ow = ow0 + owl;
        int kh = oh >> 1, kw = ow >> 1;
        int ha, hb, ta, tb; float wha, wwa;
        if (oh & 1) { ha = kh;     hb = kh + 1; wha = 0.75f; }
        else        { ha = kh - 1; hb = kh;     wha = 0.25f; }
        if (ow & 1) { ta = kw;     tb = kw + 1; wwa = 0.75f; }
        else        { ta = kw - 1; tb = kw;     wwa = 0.25f; }
        ha = min(max(ha, 0), HP - 1) - (k0 - 1);
        hb = min(max(hb, 0), HP - 1) - (k0 - 1);
        ta = min(max(ta, 0), WP - 1) - (w0 - 1);
        tb = min(max(tb, 0), WP - 1) - (w0 - 1);
        float whb = 1.f - wha, wwb = 1.f - wwa;
        float v = wha * (wwa * yS[c][ha][ta] + wwb * yS[c][ha][tb])
                + whb * (wwa * yS[c][hb][ta] + wwb * yS[c][hb][tb]);
        out[((b*16 + c)*224 + oh)*224 + ow] = v;
    }
}

extern "C" void kernel_launch(void* const* d_in, const int* in_sizes, int n_in,
                              void* d_out, int out_size, void* d_ws, size_t ws_size,
                              hipStream_t stream) {
    const float* x   = (const float*)d_in[0];
    const float* wts = (const float*)d_in[1];
    const float* fcw = (const float*)d_in[2];
    const float* fcb = (const float*)d_in[3];
    const float* lng = (const float*)d_in[4];
    const float* lnb = (const float*)d_in[5];
    float* G   = (float*)d_ws;        // 384 floats
    float* out = (float*)d_out;

    build_G<<<1, 64, 0, stream>>>(wts, G);
    fused<<<dim3(7, 14, 8), 256, 0, stream>>>(x, fcw, fcb, lng, lnb, G, out);
}

// Round 3
// 86.774 us; speedup vs baseline: 1.3077x; 1.2271x over previous
//
#include <hip/hip_runtime.h>
#include <math.h>

// QuantumConv: per-pixel 6-qubit circuit collapses to 6 real 8x8 quadratic
// forms q_w = r^T G_w r (subspace trick: wires 3-5 start at |0>, circuit
// unitary depends only on `weights`). Kernel 1 builds G (1.5 KB) from the
// weights; kernel 2 fuses pool+quantum+fc+LN+ReLU+bilinear-2x-upsample.
//
// R3: build_G at 512 threads (8 waves, one subspace column per wave ->
// per-wave gate chain is 8x shorter; was issue-bound on a single wave).
// fused upsample rewritten to float4 stores (8 wide stores/thread instead
// of 32 scalar iterations).

#define HP 112   // low-res H (=224/2)
#define WP 112

// ---------------- Kernel 1: build G[6][8][8] from weights ----------------
__global__ __launch_bounds__(512) void build_G(const float* __restrict__ wts,
                                               float* __restrict__ G) {
    __shared__ float  U[24][8];    // per-gate 2x2 complex (re,im): U00 U01 U10 U11
    __shared__ float2 cs[64][9];   // V[s][a] (+1 pad: conflict-free stage-out)
    int t = threadIdx.x;
    int lane = t & 63, wv = t >> 6;   // wave wv owns subspace column a=wv

    if (t < 24) {   // one gate per thread: Rot(phi, theta, omega)
        float phi = wts[t*3+0], th = wts[t*3+1], om = wts[t*3+2];
        float cth, sth, cap, sap, cam, sam;
        sincosf(0.5f*th, &sth, &cth);
        sincosf(0.5f*(phi+om), &sap, &cap);   // ep = cap - i*sap
        sincosf(0.5f*(phi-om), &sam, &cam);   // em = cam - i*sam
        U[t][0] =  cap*cth; U[t][1] = -sap*cth;   // U00 = ep*c
        U[t][2] = -cam*sth; U[t][3] = -sam*sth;   // U01 = -conj(em)*s
        U[t][4] =  cam*sth; U[t][5] = -sam*sth;   // U10 = em*s
        U[t][6] =  cap*cth; U[t][7] =  sap*cth;   // U11 = conj(ep)*c
    }
    __syncthreads();

    // lane = state index; v = amplitude of column wv (basis state wv<<3)
    float2 v = make_float2((lane == (wv << 3)) ? 1.0f : 0.0f, 0.0f);

    for (int l = 0; l < 4; ++l) {
        // single-qubit rotations (wire 0 = MSB, mask 1<<(5-w))
        for (int w = 0; w < 6; ++w) {
            int g = l*6 + w, m = 1 << (5 - w);
            bool hi = (lane & m) != 0;
            float csr = hi ? U[g][6] : U[g][0], csi = hi ? U[g][7] : U[g][1];
            float cpr = hi ? U[g][4] : U[g][2], cpi = hi ? U[g][5] : U[g][3];
            float px = __shfl_xor(v.x, m), py = __shfl_xor(v.y, m);
            v = make_float2(csr*v.x - csi*v.y + cpr*px - cpi*py,
                            csr*v.y + csi*v.x + cpr*py + cpi*px);
        }
        // CNOT ring: control w, target (w+r)%6 — swap target bit where control=1
        int r = l % 5 + 1;
        for (int w = 0; w < 6; ++w) {
            int mc = 1 << (5 - w), mt = 1 << (5 - ((w + r) % 6));
            float px = __shfl_xor(v.x, mt), py = __shfl_xor(v.y, mt);
            if (lane & mc) v = make_float2(px, py);
        }
    }

    cs[lane][wv] = v;
    __syncthreads();

    // G_w[a][b] = Re( i^(pop(a)-pop(b)) * sum_s z_w(s) conj(V[s,a]) V[s,b] )
    if (t < 384) {
        int w = t >> 6, a = (t >> 3) & 7, bb = t & 7;
        int mw = 1 << (5 - w);
        float re = 0.f, im = 0.f;
        for (int s = 0; s < 64; ++s) {
            float z = (s & mw) ? -1.f : 1.f;
            float2 va = cs[s][a], vb = cs[s][bb];
            re += z * (va.x*vb.x + va.y*vb.y);
            im += z * (va.x*vb.y - va.y*vb.x);
        }
        int d = (__popc(a) - __popc(bb)) & 3;   // conj(f_a)*f_b = i^d
        G[t] = (d == 0) ? re : (d == 1) ? -im : (d == 2) ? -re : im;
    }
}

// ---------------- Kernel 2: fused pool+quantum+fc+LN+ReLU+upsample ----------------
// Block: batch b, 16(oh) x 32(ow) output tile -> needs 10 x 18 low-res y tile.
__global__ __launch_bounds__(256) void fused(
    const float* __restrict__ x, const float* __restrict__ fcw,
    const float* __restrict__ fcb, const float* __restrict__ lng,
    const float* __restrict__ lnb, const float* __restrict__ G,
    float* __restrict__ out) {

    __shared__ __align__(16) float Gs[384];
    __shared__ float fcwS[96], fcbS[16], lngS[16], lnbS[16];
    __shared__ float yS[16][10][18];   // [c][row][col]

    int tid = threadIdx.x;
    int b   = blockIdx.z;
    int ow0 = blockIdx.x * 32, oh0 = blockIdx.y * 16;
    int w0  = blockIdx.x * 16, k0  = blockIdx.y * 8;   // low-res tile origin

    for (int i = tid; i < 384; i += 256) Gs[i] = G[i];
    for (int i = tid; i < 96;  i += 256) fcwS[i] = fcw[i];
    if (tid < 16) { fcbS[tid] = fcb[tid]; lngS[tid] = lng[tid]; lnbS[tid] = lnb[tid]; }
    __syncthreads();

    if (tid < 180) {   // 10 x 18 low-res pixels (1-halo for bilinear)
        int pr = tid / 18, pc = tid % 18;
        int ih = min(max(k0 - 1 + pr, 0), HP - 1);
        int iw = min(max(w0 - 1 + pc, 0), WP - 1);

        // 2x2 mean pool, 3 channels
        float m[3];
        #pragma unroll
        for (int c = 0; c < 3; ++c) {
            const float2* px = reinterpret_cast<const float2*>(
                x + (((b*3 + c)*224 + 2*ih)*224 + 2*iw));
            float2 r0 = px[0], r1 = px[112];
            m[c] = 0.25f * (r0.x + r0.y + r1.x + r1.y);
        }

        float cc[3], ssn[3];
        #pragma unroll
        for (int c = 0; c < 3; ++c) sincosf(0.5f*m[c], &ssn[c], &cc[c]);

        float r8[8] = { cc[0]*cc[1]*cc[2], cc[0]*cc[1]*ssn[2],
                        cc[0]*ssn[1]*cc[2], cc[0]*ssn[1]*ssn[2],
                        ssn[0]*cc[1]*cc[2], ssn[0]*cc[1]*ssn[2],
                        ssn[0]*ssn[1]*cc[2], ssn[0]*ssn[1]*ssn[2] };

        // q_w = r^T G_w r  (ds_read_b128 on Gs)
        float q[6];
        const float4* G4 = reinterpret_cast<const float4*>(Gs);
        #pragma unroll
        for (int w = 0; w < 6; ++w) {
            float acc = 0.f;
            #pragma unroll
            for (int a = 0; a < 8; ++a) {
                float4 g0 = G4[w*16 + a*2], g1 = G4[w*16 + a*2 + 1];
                float d = g0.x*r8[0] + g0.y*r8[1] + g0.z*r8[2] + g0.w*r8[3]
                        + g1.x*r8[4] + g1.y*r8[5] + g1.z*r8[6] + g1.w*r8[7];
                acc += r8[a] * d;
            }
            q[w] = acc;
        }

        // fc -> LayerNorm -> ReLU
        float y[16]; float mu = 0.f;
        #pragma unroll
        for (int c = 0; c < 16; ++c) {
            float v = fcbS[c];
            #pragma unroll
            for (int w = 0; w < 6; ++w) v += fcwS[c*6 + w] * q[w];
            y[c] = v; mu += v;
        }
        mu *= 0.0625f;
        float var = 0.f;
        #pragma unroll
        for (int c = 0; c < 16; ++c) { float d = y[c] - mu; var += d*d; }
        var *= 0.0625f;
        float inv = 1.0f / sqrtf(var + 1e-5f);
        #pragma unroll
        for (int c = 0; c < 16; ++c) {
            float vv = (y[c] - mu) * inv * lngS[c] + lnbS[c];
            yS[c][pr][pc] = fmaxf(vv, 0.f);
        }
    }
    __syncthreads();

    // bilinear 2x upsample, float4 stores. 2048 float4s / 256 threads = 8 each.
    // Per 4 consecutive outputs (ow..ow+3, ow%4==0, kw=ow/2):
    //   cols needed: kw-1, kw, kw+1, kw+2 (clamped); weights 0.25/0.75 pattern.
    #pragma unroll
    for (int k = 0; k < 8; ++k) {
        int it = tid + k * 256;
        int c = it >> 7, rem = it & 127, ohl = rem >> 3, owg = rem & 7;
        int oh = oh0 + ohl, ow = ow0 + owg * 4;
        int kh = oh >> 1, kw = ow >> 1;

        int ha, hb; float wha;
        if (oh & 1) { ha = kh;     hb = min(kh + 1, HP - 1); wha = 0.75f; }
        else        { ha = max(kh - 1, 0); hb = kh;          wha = 0.25f; }
        ha -= (k0 - 1); hb -= (k0 - 1);
        float whb = 1.f - wha;

        int t0 = max(kw - 1, 0)      - (w0 - 1);
        int t1 = kw                  - (w0 - 1);
        int t2 = kw + 1              - (w0 - 1);
        int t3 = min(kw + 2, WP - 1) - (w0 - 1);

        float va0 = wha * yS[c][ha][t0] + whb * yS[c][hb][t0];
        float va1 = wha * yS[c][ha][t1] + whb * yS[c][hb][t1];
        float va2 = wha * yS[c][ha][t2] + whb * yS[c][hb][t2];
        float va3 = wha * yS[c][ha][t3] + whb * yS[c][hb][t3];

        float4 o;
        o.x = 0.25f * va0 + 0.75f * va1;
        o.y = 0.75f * va1 + 0.25f * va2;
        o.z = 0.25f * va1 + 0.75f * va2;
        o.w = 0.75f * va2 + 0.25f * va3;
        *reinterpret_cast<float4*>(out + (((b*16 + c)*224 + oh)*224 + ow)) = o;
    }
}

extern "C" void kernel_launch(void* const* d_in, const int* in_sizes, int n_in,
                              void* d_out, int out_size, void* d_ws, size_t ws_size,
                              hipStream_t stream) {
    const float* x   = (const float*)d_in[0];
    const float* wts = (const float*)d_in[1];
    const float* fcw = (const float*)d_in[2];
    const float* fcb = (const float*)d_in[3];
    const float* lng = (const float*)d_in[4];
    const float* lnb = (const float*)d_in[5];
    float* G   = (float*)d_ws;        // 384 floats
    float* out = (float*)d_out;

    build_G<<<1, 512, 0, stream>>>(wts, G);
    fused<<<dim3(7, 14, 8), 256, 0, stream>>>(x, fcw, fcb, lng, lnb, G, out);
}

// Round 4
// 84.460 us; speedup vs baseline: 1.3436x; 1.0274x over previous
//
#include <hip/hip_runtime.h>
#include <math.h>

// QuantumConv: per-pixel 6-qubit circuit collapses to 6 real symmetric 8x8
// quadratic forms q_w = r^T G_w r (subspace trick: wires 3-5 start at |0>,
// circuit unitary depends only on `weights`). Kernel 1 builds the packed
// symmetrized S[6][36] (triangular, diag x1 / off-diag x2) from the weights;
// kernel 2 fuses pool+quantum+fc+LN+ReLU+bilinear-2x-upsample.
//
// R4: (1) symmetry packing — 36 shared products p[ab]=r_a*r_b + 216 FMA
// replaces 768 FMA / 96 LDS reads; (2) __sincosf (native v_sin/v_cos,
// angles are O(1) so no range-reduction needed).

#define HP 112   // low-res H (=224/2)
#define WP 112

// ---------------- Kernel 1: build S[6][36] from weights ----------------
__global__ __launch_bounds__(512) void build_G(const float* __restrict__ wts,
                                               float* __restrict__ S) {
    __shared__ float  U[24][8];    // per-gate 2x2 complex (re,im): U00 U01 U10 U11
    __shared__ float2 cs[64][9];   // V[s][a] (+1 pad: conflict-free stage-out)
    int t = threadIdx.x;
    int lane = t & 63, wv = t >> 6;   // wave wv owns subspace column a=wv

    if (t < 24) {   // one gate per thread: Rot(phi, theta, omega)
        float phi = wts[t*3+0], th = wts[t*3+1], om = wts[t*3+2];
        float cth, sth, cap, sap, cam, sam;
        sincosf(0.5f*th, &sth, &cth);
        sincosf(0.5f*(phi+om), &sap, &cap);   // ep = cap - i*sap
        sincosf(0.5f*(phi-om), &sam, &cam);   // em = cam - i*sam
        U[t][0] =  cap*cth; U[t][1] = -sap*cth;   // U00 = ep*c
        U[t][2] = -cam*sth; U[t][3] = -sam*sth;   // U01 = -conj(em)*s
        U[t][4] =  cam*sth; U[t][5] = -sam*sth;   // U10 = em*s
        U[t][6] =  cap*cth; U[t][7] =  sap*cth;   // U11 = conj(ep)*c
    }
    __syncthreads();

    // lane = state index; v = amplitude of column wv (basis state wv<<3)
    float2 v = make_float2((lane == (wv << 3)) ? 1.0f : 0.0f, 0.0f);

    for (int l = 0; l < 4; ++l) {
        // single-qubit rotations (wire 0 = MSB, mask 1<<(5-w))
        for (int w = 0; w < 6; ++w) {
            int g = l*6 + w, m = 1 << (5 - w);
            bool hi = (lane & m) != 0;
            float csr = hi ? U[g][6] : U[g][0], csi = hi ? U[g][7] : U[g][1];
            float cpr = hi ? U[g][4] : U[g][2], cpi = hi ? U[g][5] : U[g][3];
            float px = __shfl_xor(v.x, m), py = __shfl_xor(v.y, m);
            v = make_float2(csr*v.x - csi*v.y + cpr*px - cpi*py,
                            csr*v.y + csi*v.x + cpr*py + cpi*px);
        }
        // CNOT ring: control w, target (w+r)%6 — swap target bit where control=1
        int r = l % 5 + 1;
        for (int w = 0; w < 6; ++w) {
            int mc = 1 << (5 - w), mt = 1 << (5 - ((w + r) % 6));
            float px = __shfl_xor(v.x, mt), py = __shfl_xor(v.y, mt);
            if (lane & mc) v = make_float2(px, py);
        }
    }

    cs[lane][wv] = v;
    __syncthreads();

    // G_w[a][b] = Re( i^(pop(a)-pop(b)) * sum_s z_w(s) conj(V[s,a]) V[s,b] )
    // Symmetric in (a,b) -> pack upper triangle, off-diag doubled.
    if (t < 384) {
        int w = t >> 6, a = (t >> 3) & 7, bb = t & 7;
        if (a <= bb) {
            int mw = 1 << (5 - w);
            float re = 0.f, im = 0.f;
            for (int s = 0; s < 64; ++s) {
                float z = (s & mw) ? -1.f : 1.f;
                float2 va = cs[s][a], vb = cs[s][bb];
                re += z * (va.x*vb.x + va.y*vb.y);
                im += z * (va.x*vb.y - va.y*vb.x);
            }
            int d = (__popc(a) - __popc(bb)) & 3;   // conj(f_a)*f_b = i^d
            float g = (d == 0) ? re : (d == 1) ? -im : (d == 2) ? -re : im;
            int idx = 8*a - (a*(a-1))/2 + (bb - a);   // triangular index, 0..35
            S[w*36 + idx] = (a == bb) ? g : 2.0f*g;
        }
    }
}

// ---------------- Kernel 2: fused pool+quantum+fc+LN+ReLU+upsample ----------------
// Block: batch b, 16(oh) x 32(ow) output tile -> needs 10 x 18 low-res y tile.
__global__ __launch_bounds__(256) void fused(
    const float* __restrict__ x, const float* __restrict__ fcw,
    const float* __restrict__ fcb, const float* __restrict__ lng,
    const float* __restrict__ lnb, const float* __restrict__ S,
    float* __restrict__ out) {

    __shared__ __align__(16) float Ss[216];
    __shared__ float fcwS[96], fcbS[16], lngS[16], lnbS[16];
    __shared__ float yS[16][10][18];   // [c][row][col]

    int tid = threadIdx.x;
    int b   = blockIdx.z;
    int ow0 = blockIdx.x * 32, oh0 = blockIdx.y * 16;
    int w0  = blockIdx.x * 16, k0  = blockIdx.y * 8;   // low-res tile origin

    if (tid < 216) Ss[tid] = S[tid];
    for (int i = tid; i < 96;  i += 256) fcwS[i] = fcw[i];
    if (tid < 16) { fcbS[tid] = fcb[tid]; lngS[tid] = lng[tid]; lnbS[tid] = lnb[tid]; }
    __syncthreads();

    if (tid < 180) {   // 10 x 18 low-res pixels (1-halo for bilinear)
        int pr = tid / 18, pc = tid % 18;
        int ih = min(max(k0 - 1 + pr, 0), HP - 1);
        int iw = min(max(w0 - 1 + pc, 0), WP - 1);

        // 2x2 mean pool, 3 channels
        float m[3];
        #pragma unroll
        for (int c = 0; c < 3; ++c) {
            const float2* px = reinterpret_cast<const float2*>(
                x + (((b*3 + c)*224 + 2*ih)*224 + 2*iw));
            float2 r0 = px[0], r1 = px[112];
            m[c] = 0.25f * (r0.x + r0.y + r1.x + r1.y);
        }

        float cc[3], ssn[3];
        #pragma unroll
        for (int c = 0; c < 3; ++c) __sincosf(0.5f*m[c], &ssn[c], &cc[c]);

        float r8[8] = { cc[0]*cc[1]*cc[2], cc[0]*cc[1]*ssn[2],
                        cc[0]*ssn[1]*cc[2], cc[0]*ssn[1]*ssn[2],
                        ssn[0]*cc[1]*cc[2], ssn[0]*cc[1]*ssn[2],
                        ssn[0]*ssn[1]*cc[2], ssn[0]*ssn[1]*ssn[2] };

        // 36 shared products (upper triangle of r r^T)
        float p[36];
        {
            int k = 0;
            #pragma unroll
            for (int a = 0; a < 8; ++a)
                #pragma unroll
                for (int bb = a; bb < 8; ++bb) p[k++] = r8[a]*r8[bb];
        }

        // q_w = dot(S_w, p), 9 x ds_read_b128 per wire
        float q[6];
        #pragma unroll
        for (int w = 0; w < 6; ++w) {
            const float4* S4 = reinterpret_cast<const float4*>(Ss + w*36);
            float acc = 0.f;
            #pragma unroll
            for (int j = 0; j < 9; ++j) {
                float4 s4 = S4[j];
                acc += s4.x*p[j*4+0] + s4.y*p[j*4+1]
                     + s4.z*p[j*4+2] + s4.w*p[j*4+3];
            }
            q[w] = acc;
        }

        // fc -> LayerNorm -> ReLU
        float y[16]; float mu = 0.f;
        #pragma unroll
        for (int c = 0; c < 16; ++c) {
            float v = fcbS[c];
            #pragma unroll
            for (int w = 0; w < 6; ++w) v += fcwS[c*6 + w] * q[w];
            y[c] = v; mu += v;
        }
        mu *= 0.0625f;
        float var = 0.f;
        #pragma unroll
        for (int c = 0; c < 16; ++c) { float d = y[c] - mu; var += d*d; }
        var *= 0.0625f;
        float inv = 1.0f / sqrtf(var + 1e-5f);
        #pragma unroll
        for (int c = 0; c < 16; ++c) {
            float vv = (y[c] - mu) * inv * lngS[c] + lnbS[c];
            yS[c][pr][pc] = fmaxf(vv, 0.f);
        }
    }
    __syncthreads();

    // bilinear 2x upsample, float4 stores. 2048 float4s / 256 threads = 8 each.
    #pragma unroll
    for (int k = 0; k < 8; ++k) {
        int it = tid + k * 256;
        int c = it >> 7, rem = it & 127, ohl = rem >> 3, owg = rem & 7;
        int oh = oh0 + ohl, ow = ow0 + owg * 4;
        int kh = oh >> 1, kw = ow >> 1;

        int ha, hb; float wha;
        if (oh & 1) { ha = kh;     hb = min(kh + 1, HP - 1); wha = 0.75f; }
        else        { ha = max(kh - 1, 0); hb = kh;          wha = 0.25f; }
        ha -= (k0 - 1); hb -= (k0 - 1);
        float whb = 1.f - wha;

        int t0 = max(kw - 1, 0)      - (w0 - 1);
        int t1 = kw                  - (w0 - 1);
        int t2 = kw + 1              - (w0 - 1);
        int t3 = min(kw + 2, WP - 1) - (w0 - 1);

        float va0 = wha * yS[c][ha][t0] + whb * yS[c][hb][t0];
        float va1 = wha * yS[c][ha][t1] + whb * yS[c][hb][t1];
        float va2 = wha * yS[c][ha][t2] + whb * yS[c][hb][t2];
        float va3 = wha * yS[c][ha][t3] + whb * yS[c][hb][t3];

        float4 o;
        o.x = 0.25f * va0 + 0.75f * va1;
        o.y = 0.75f * va1 + 0.25f * va2;
        o.z = 0.25f * va1 + 0.75f * va2;
        o.w = 0.75f * va2 + 0.25f * va3;
        *reinterpret_cast<float4*>(out + (((b*16 + c)*224 + oh)*224 + ow)) = o;
    }
}

extern "C" void kernel_launch(void* const* d_in, const int* in_sizes, int n_in,
                              void* d_out, int out_size, void* d_ws, size_t ws_size,
                              hipStream_t stream) {
    const float* x   = (const float*)d_in[0];
    const float* wts = (const float*)d_in[1];
    const float* fcw = (const float*)d_in[2];
    const float* fcb = (const float*)d_in[3];
    const float* lng = (const float*)d_in[4];
    const float* lnb = (const float*)d_in[5];
    float* S   = (float*)d_ws;        // 216 floats (packed symmetric G)
    float* out = (float*)d_out;

    build_G<<<1, 512, 0, stream>>>(wts, S);
    fused<<<dim3(7, 14, 8), 256, 0, stream>>>(x, fcw, fcb, lng, lnb, S, out);
}